// Round 9
// baseline (2951.367 us; speedup 1.0000x reference)
//
#include <hip/hip_runtime.h>
#include <math.h>

#define HD 768
#define NR 8
#define NB 8
#define SL 512
#define NE 64
#define NTOK 4096
#define NSR 32768
#define GRID 768
#define NWAVES 3072
#define CREW 32               // chain-crew blocks
#define SRW 2944              // sr-stream waves = (GRID-CREW)*4
#define AGT __HIP_MEMORY_SCOPE_AGENT

struct Args {
  const float *labels, *sr, *tok, *ent, *mask;
  const int *e2t, *t2e;
  const float *Wsing, *bsing, *Wmult, *bmult, *Wans, *bans;
  float *ws;
  float *out;
};

__device__ __forceinline__ float wred(float v) {
  #pragma unroll
  for (int m = 32; m >= 1; m >>= 1) v += __shfl_xor(v, m, 64);
  return v;
}
__device__ __forceinline__ double wredd(double v) {
  #pragma unroll
  for (int m = 32; m >= 1; m >>= 1) v += __shfl_xor(v, m, 64);
  return v;
}

// agent-scope atomics: bypass the (non-coherent) per-XCD L2 -> no fences needed
__device__ __forceinline__ float aload(const float* p) {
  return __hip_atomic_load((float*)p, __ATOMIC_RELAXED, AGT);
}
__device__ __forceinline__ double aloadd(const double* p) {
  return __hip_atomic_load((double*)p, __ATOMIC_RELAXED, AGT);
}
__device__ __forceinline__ void astore(float* p, float v) {
  __hip_atomic_store(p, v, __ATOMIC_RELAXED, AGT);
}
__device__ __forceinline__ void astore_rel(float* p, float v) {
  __hip_atomic_store(p, v, __ATOMIC_RELEASE, AGT);
}

__device__ __forceinline__ float dot12(const float4 a0, const float4 a1, const float4 a2,
                                       const float* __restrict__ w, int lane) {
  const float4 w0 = *reinterpret_cast<const float4*>(w + lane * 4);
  const float4 w1 = *reinterpret_cast<const float4*>(w + 256 + lane * 4);
  const float4 w2 = *reinterpret_cast<const float4*>(w + 512 + lane * 4);
  float s = 0.f;
  s = fmaf(a0.x, w0.x, s); s = fmaf(a0.y, w0.y, s); s = fmaf(a0.z, w0.z, s); s = fmaf(a0.w, w0.w, s);
  s = fmaf(a1.x, w1.x, s); s = fmaf(a1.y, w1.y, s); s = fmaf(a1.z, w1.z, s); s = fmaf(a1.w, w1.w, s);
  s = fmaf(a2.x, w2.x, s); s = fmaf(a2.y, w2.y, s); s = fmaf(a2.z, w2.z, s); s = fmaf(a2.w, w2.w, s);
  return s;
}

// crew barrier: 32 blocks, atomic counter + generation, NO fences (data moves via agent atomics)
__device__ __forceinline__ void chainbar(unsigned* c, unsigned* gen, int tid) {
  __syncthreads();
  if (tid == 0) {
    unsigned g = __hip_atomic_load(gen, __ATOMIC_ACQUIRE, AGT);
    if (__hip_atomic_fetch_add(c, 1u, __ATOMIC_ACQ_REL, AGT) == CREW - 1) {
      __hip_atomic_store(c, 0u, __ATOMIC_RELAXED, AGT);
      __hip_atomic_fetch_add(gen, 1u, __ATOMIC_ACQ_REL, AGT);
    } else {
      while (__hip_atomic_load(gen, __ATOMIC_ACQUIRE, AGT) == g)
        __builtin_amdgcn_s_sleep(1);
    }
  }
  __syncthreads();
}

__global__ void init_kernel(unsigned* B) {
  if (threadIdx.x < 16) B[threadIdx.x] = 0u;
}

__global__ __launch_bounds__(256, 3) void fused_kernel(Args A) {
  __shared__ float smem[10752];  // 43 KB: chain u-stage (768) | v-stage (10752) | phase-8 sc+wsum (time-disjoint)
  const int tid  = threadIdx.x;
  const int lane = tid & 63;
  const int wid  = tid >> 6;
  const int bid  = blockIdx.x;

  unsigned* SY = (unsigned*)A.ws;        // [0]=chain_c [1]=chain_gen [2]=chain_done [3]=all_done [4]=fin
  float* F    = A.ws;
  float* msum = F + 16;
  double* pbce = (double*)(F + 24);      // 8 doubles, byte 96 (8B aligned)
  float* uS  = F + 64;          float* uM  = uS + 8 * HD;
  float* vS  = uM + 8 * HD;     float* vM  = vS + 7 * HD;   // vS,vM contiguous (10752 floats)
  float* buS = vM + 7 * HD;     float* buM = buS + 8;
  float* as_ = F + 23168;       float* am_ = as_ + NSR;
  float* ps  = am_ + NSR;       float* pm  = ps + 7 * NTOK;
  float* dts = pm + 7 * NTOK;   float* dem = dts + NTOK;

  if (bid < CREW) {
    // ---- chain crew: 7 phases; each block owns 96 rowdots of one band ----
    const int tbase   = bid * 96;        // tasks tbase..tbase+95
    const int band    = tbase / 768;     // 0:uS-chain 1:uM-chain 2:vS 3:vM
    const int cm      = band & 1;
    const int ischain = (band < 2);
    const int row0    = (tbase % 768) + wid * 24;
    for (int p = 0; p < 7; ++p) {
      // stage the one u_p this block needs into smem[0..767]
      if (p == 0) {
        const float* u0 = (cm ? A.Wmult : A.Wsing) + 2 * HD;   // pre-answer weight slice (plain: input)
        for (int i = tid; i < HD; i += 256) smem[i] = u0[i];
      } else {
        const float* up = (cm ? uM : uS) + p * HD;
        for (int i = tid; i < HD; i += 256) smem[i] = aload(up + i);
      }
      __syncthreads();
      if (!ischain || p < 6) {           // u_7 never needed
        for (int i = 0; i < 24; ++i) {
          const int row = row0 + i;
          const float* wr = A.Wans + (size_t)(ischain ? HD + row : row) * HD;
          const float4 a0 = *reinterpret_cast<const float4*>(wr + lane * 4);
          const float4 a1 = *reinterpret_cast<const float4*>(wr + 256 + lane * 4);
          const float4 a2 = *reinterpret_cast<const float4*>(wr + 512 + lane * 4);
          float acc = wred(dot12(a0, a1, a2, smem, lane));
          if (lane == 0) {
            if (ischain) astore_rel((cm ? uM : uS) + (p + 1) * HD + row, acc);
            else         astore_rel((cm ? vM : vS) + p * HD + row, acc);
          }
        }
      }
      if ((bid == 0 || bid == 8) && wid == 0) {   // bu_p = b_ans . u_p (block0: S, block8: M)
        const float4 b0 = *reinterpret_cast<const float4*>(A.bans + lane * 4);
        const float4 b1 = *reinterpret_cast<const float4*>(A.bans + 256 + lane * 4);
        const float4 b2 = *reinterpret_cast<const float4*>(A.bans + 512 + lane * 4);
        float acc = wred(dot12(b0, b1, b2, smem, lane));
        if (lane == 0) astore_rel((bid == 8 ? buM : buS) + p, acc);
      }
      chainbar(SY + 0, SY + 1, tid);
    }
    if (bid == 0 && tid == 0)
      __hip_atomic_store(SY + 2, 1u, __ATOMIC_RELEASE, AGT);   // chain_done
  } else {
    // ---- sr stream: no barriers ----
    if (bid == CREW && wid == 0) {       // mask sum (extra duty)
      const float4* m4 = (const float4*)A.mask;
      float sm = 0.f;
      for (int i = lane; i < NTOK / 4; i += 64) {
        float4 v = m4[i];
        sm += v.x + v.y + v.z + v.w;
      }
      sm = wred(sm);
      if (lane == 0) astore(msum, sm);
    }
    const int w = (bid - CREW) * 4 + wid;          // 0..2943
    for (int r = w; r < NSR; r += SRW) {
      const float* row = A.sr + (size_t)r * HD;
      const float4 x0 = *reinterpret_cast<const float4*>(row + lane * 4);
      const float4 x1 = *reinterpret_cast<const float4*>(row + 256 + lane * 4);
      const float4 x2 = *reinterpret_cast<const float4*>(row + 512 + lane * 4);
      float aS = wred(dot12(x0, x1, x2, A.Wsing, lane));
      float aM = wred(dot12(x0, x1, x2, A.Wmult, lane));
      if (lane == 0) { astore(as_ + r, aS); astore(am_ + r, aM); }
    }
    if (tid == 0) {                      // wait for chain outputs
      while (__hip_atomic_load(SY + 2, __ATOMIC_ACQUIRE, AGT) == 0u)
        __builtin_amdgcn_s_sleep(8);
    }
    __syncthreads();
  }

  // ---- v-stage (all blocks): vS|vM -> LDS via coherent atomic loads ----
  for (int i = tid; i < 10752; i += 256) smem[i] = aload(vS + i);
  __syncthreads();

  // ---- token dots: global wave stripe over 4096 tokens ----
  const int g = bid * 4 + wid;
  for (int t = g; t < NTOK; t += NWAVES) {
    const float* tr = A.tok + (size_t)t * HD;
    const float* er = A.ent + (size_t)t * HD;
    const float4 t0 = *reinterpret_cast<const float4*>(tr + lane * 4);
    const float4 t1 = *reinterpret_cast<const float4*>(tr + 256 + lane * 4);
    const float4 t2 = *reinterpret_cast<const float4*>(tr + 512 + lane * 4);
    const float4 e0 = *reinterpret_cast<const float4*>(er + lane * 4);
    const float4 e1 = *reinterpret_cast<const float4*>(er + 256 + lane * 4);
    const float4 e2 = *reinterpret_cast<const float4*>(er + 512 + lane * 4);
    float dtsv = wred(dot12(t0, t1, t2, A.Wsing + HD, lane));
    float demv = wred(dot12(e0, e1, e2, A.Wmult + HD, lane));
    if (lane == 0) { astore(dts + t, dtsv); astore(dem + t, demv); }
    #pragma unroll
    for (int k = 0; k < 7; ++k) {
      float a = wred(dot12(t0, t1, t2, smem + k * HD, lane));
      float b = wred(dot12(t0, t1, t2, smem + 5376 + k * HD, lane));
      if (lane == 0) { astore(ps + k * NTOK + t, a); astore(pm + k * NTOK + t, b); }
    }
  }
  __syncthreads();
  if (tid == 0) __hip_atomic_fetch_add(SY + 3, 1u, __ATOMIC_ACQ_REL, AGT);  // all_done
  if (bid >= NB) return;

  // ---- phase 8: per-batch recurrence (blocks 0..7) ----
  if (tid == 0) {
    while (__hip_atomic_load(SY + 3, __ATOMIC_ACQUIRE, AGT) < (unsigned)GRID)
      __builtin_amdgcn_s_sleep(8);
  }
  __syncthreads();
  unsigned* sc = (unsigned*)smem;          // [8][64]
  double* wsum = (double*)(smem + 512);    // byte 2048, aligned
  const int b = bid;
  const int t0 = b * SL + tid, t1 = t0 + 256;
  sc[tid] = 0u; sc[tid + 256] = 0u;
  float ps0[7], pm0[7], ps1[7], pm1[7], as0[8], am0[8], as1[8], am1[8], buSv[7], buMv[7];
  #pragma unroll
  for (int k = 0; k < 7; ++k) {
    ps0[k] = aload(ps + k * NTOK + t0); pm0[k] = aload(pm + k * NTOK + t0);
    ps1[k] = aload(ps + k * NTOK + t1); pm1[k] = aload(pm + k * NTOK + t1);
    buSv[k] = aload(buS + k); buMv[k] = aload(buM + k);
  }
  #pragma unroll
  for (int r = 0; r < 8; ++r) {
    as0[r] = aload(as_ + r * NTOK + t0); am0[r] = aload(am_ + r * NTOK + t0);
    as1[r] = aload(as_ + r * NTOK + t1); am1[r] = aload(am_ + r * NTOK + t1);
  }
  const float dts0 = aload(dts + t0), dem0 = aload(dem + t0);
  const float dts1 = aload(dts + t1), dem1 = aload(dem + t1);
  const float b1 = A.bsing[0], b2 = A.bmult[0];
  const int e0i = A.e2t[t0] & (NE - 1), e1i = A.e2t[t1] & (NE - 1);
  const int q0 = A.t2e[t0] & (NE - 1), q1 = A.t2e[t1] & (NE - 1);
  __syncthreads();

  float m0[8], m1[8];
  float cs = 0.f, cmv = 0.f;
  double bsum = 0.0;
  #pragma unroll
  for (int r = 0; r < 8; ++r) {
    float As0 = cs, Am0 = cmv, As1 = cs, Am1 = cmv;
    #pragma unroll
    for (int j = 0; j < r; ++j) {
      As0 = fmaf(m0[j], ps0[r - 1 - j], As0); Am0 = fmaf(m0[j], pm0[r - 1 - j], Am0);
      As1 = fmaf(m1[j], ps1[r - 1 - j], As1); Am1 = fmaf(m1[j], pm1[r - 1 - j], Am1);
    }
    const float sing0 = 1.f / (1.f + expf(-(as0[r] + dts0 + As0 + b1)));
    const float mult0 = 1.f / (1.f + expf(-(am0[r] + dem0 + Am0 + b2)));
    const float sing1 = 1.f / (1.f + expf(-(as1[r] + dts1 + As1 + b1)));
    const float mult1 = 1.f / (1.f + expf(-(am1[r] + dem1 + Am1 + b2)));
    atomicMax(&sc[r * NE + e0i], __float_as_uint(mult0));  // mult>0: uint order == float order
    atomicMax(&sc[r * NE + e1i], __float_as_uint(mult1));
    __syncthreads();
    const float mg0 = fmaxf(sing0, __uint_as_float(sc[r * NE + q0]));
    const float mg1 = fmaxf(sing1, __uint_as_float(sc[r * NE + q1]));
    m0[r] = mg0; m1[r] = mg1;
    A.out[1 + r * NTOK + t0] = mg0;
    A.out[1 + r * NTOK + t1] = mg1;
    const float la0 = A.labels[r * NTOK + t0], la1 = A.labels[r * NTOK + t1];
    const float p0 = fminf(fmaxf(mg0, 1e-7f), 1.f - 1e-7f);
    const float p1 = fminf(fmaxf(mg1, 1e-7f), 1.f - 1e-7f);
    bsum += (double)(-(la0 * logf(p0) + (1.f - la0) * log1pf(-p0)));
    bsum += (double)(-(la1 * logf(p1) + (1.f - la1) * log1pf(-p1)));
    if (r < 7) { cs += buSv[r]; cmv += buMv[r]; }
  }
  bsum = wredd(bsum);
  if ((tid & 63) == 0) wsum[tid >> 6] = bsum;
  __syncthreads();
  if (tid == 0) {
    double tot8 = wsum[0] + wsum[1] + wsum[2] + wsum[3];
    __hip_atomic_store(pbce + b, tot8, __ATOMIC_RELEASE, AGT);
    unsigned k = __hip_atomic_fetch_add(SY + 4, 1u, __ATOMIC_ACQ_REL, AGT);
    if (k == NB - 1) {                   // last step-block finalizes the loss
      double tot = 0.0;
      #pragma unroll
      for (int i = 0; i < 8; ++i) tot += aloadd(pbce + i);
      A.out[0] = (float)(tot * (double)aload(msum) / 4096.0);
    }
  }
}

extern "C" void kernel_launch(void* const* d_in, const int* in_sizes, int n_in,
                              void* d_out, int out_size, void* d_ws, size_t ws_size,
                              hipStream_t stream) {
  (void)in_sizes; (void)n_in; (void)out_size; (void)ws_size;
  Args a;
  a.labels = (const float*)d_in[0];
  a.sr     = (const float*)d_in[1];
  a.tok    = (const float*)d_in[2];
  a.ent    = (const float*)d_in[3];
  a.mask   = (const float*)d_in[4];
  a.e2t    = (const int*)d_in[5];
  a.t2e    = (const int*)d_in[6];
  a.Wsing  = (const float*)d_in[7];
  a.bsing  = (const float*)d_in[8];
  a.Wmult  = (const float*)d_in[9];
  a.bmult  = (const float*)d_in[10];
  a.Wans   = (const float*)d_in[11];
  a.bans   = (const float*)d_in[12];
  a.ws     = (float*)d_ws;
  a.out    = (float*)d_out;
  init_kernel<<<1, 64, 0, stream>>>((unsigned*)d_ws);
  fused_kernel<<<GRID, 256, 0, stream>>>(a);
}

// Round 10
// 234.488 us; speedup vs baseline: 12.5864x; 12.5864x over previous
//
#include <hip/hip_runtime.h>
#include <math.h>

#define HD 768
#define NR 8
#define NB 8
#define SL 512
#define NE 64
#define NTOK 4096
#define NSR 32768
#define AGT __HIP_MEMORY_SCOPE_AGENT

// chain+sr launch geometry: blocks 0..768 = chain tasks (3074 waves + msum), 769..1408 = sr stream
#define CGRID 1409
#define SRWAVES 2560          // (CGRID-769)*4
#define SLICE 4682            // ceil(NSR/7)

struct Args {
  const float *labels, *sr, *tok, *ent, *mask;
  const int *e2t, *t2e;
  const float *Wsing, *bsing, *Wmult, *bmult, *Wans, *bans;
  float *ws;
  float *out;
};

__device__ __forceinline__ float wred(float v) {
  #pragma unroll
  for (int m = 32; m >= 1; m >>= 1) v += __shfl_xor(v, m, 64);
  return v;
}
__device__ __forceinline__ double wredd(double v) {
  #pragma unroll
  for (int m = 32; m >= 1; m >>= 1) v += __shfl_xor(v, m, 64);
  return v;
}

__device__ __forceinline__ float dot12(const float4 a0, const float4 a1, const float4 a2,
                                       const float* __restrict__ w, int lane) {
  const float4 w0 = *reinterpret_cast<const float4*>(w + lane * 4);
  const float4 w1 = *reinterpret_cast<const float4*>(w + 256 + lane * 4);
  const float4 w2 = *reinterpret_cast<const float4*>(w + 512 + lane * 4);
  float s = 0.f;
  s = fmaf(a0.x, w0.x, s); s = fmaf(a0.y, w0.y, s); s = fmaf(a0.z, w0.z, s); s = fmaf(a0.w, w0.w, s);
  s = fmaf(a1.x, w1.x, s); s = fmaf(a1.y, w1.y, s); s = fmaf(a1.z, w1.z, s); s = fmaf(a1.w, w1.w, s);
  s = fmaf(a2.x, w2.x, s); s = fmaf(a2.y, w2.y, s); s = fmaf(a2.z, w2.z, s); s = fmaf(a2.w, w2.w, s);
  return s;
}

__device__ __forceinline__ float rowdot(const float* __restrict__ a, const float* __restrict__ w, int lane) {
  const float4 a0 = *reinterpret_cast<const float4*>(a + lane * 4);
  const float4 a1 = *reinterpret_cast<const float4*>(a + 256 + lane * 4);
  const float4 a2 = *reinterpret_cast<const float4*>(a + 512 + lane * 4);
  return wred(dot12(a0, a1, a2, w, lane));
}

// Launch k (k=1..7): compute u_k = Wb u_{k-1} (k<7), v_{k-1} = Wa u_{k-1}, bu_{k-1} = b.u_{k-1},
// plus stream sr rows [sr0, sr1). Sequencing between launches = kernel edge (only safe sync).
__global__ __launch_bounds__(256) void chain_sr_kernel(Args A, int k, int sr0, int sr1) {
  const int tid  = threadIdx.x;
  const int lane = tid & 63;
  const int gwid = blockIdx.x * 4 + (tid >> 6);

  float* F = A.ws;
  float* msum = F + 16;
  float* uS = F + 64;         float* uM = uS + 8 * HD;
  float* vS = uM + 8 * HD;    float* vM = vS + 7 * HD;
  float* buS = vM + 7 * HD;   float* buM = buS + 8;
  float* as_ = F + 23168;     float* am_ = as_ + NSR;

  if (gwid < 3074) {
    const float* uPrevS = (k == 1) ? (A.Wsing + 2 * HD) : (uS + (size_t)(k - 1) * HD);
    const float* uPrevM = (k == 1) ? (A.Wmult + 2 * HD) : (uM + (size_t)(k - 1) * HD);
    if (gwid < 1536) {                 // u_k = Wb u_{k-1}
      if (k < 7) {
        const int cm = gwid >= 768, row = gwid & 767;
        float acc = rowdot(A.Wans + (size_t)(HD + row) * HD, cm ? uPrevM : uPrevS, lane);
        if (lane == 0) (cm ? uM : uS)[(size_t)k * HD + row] = acc;
      }
    } else if (gwid < 3072) {          // v_{k-1} = Wa u_{k-1}
      const int t2 = gwid - 1536, cm = t2 >= 768, row = t2 & 767;
      float acc = rowdot(A.Wans + (size_t)row * HD, cm ? uPrevM : uPrevS, lane);
      if (lane == 0) (cm ? vM : vS)[(size_t)(k - 1) * HD + row] = acc;
    } else {                           // bu_{k-1}
      const int cm = (gwid == 3073);
      float acc = rowdot(A.bans, cm ? uPrevM : uPrevS, lane);
      if (lane == 0) (cm ? buM : buS)[k - 1] = acc;
    }
  } else if (gwid == 3074 && k == 1) { // mask sum + zero finalize counter (once, launch 1)
    const float4* m4 = (const float4*)A.mask;
    float sm = 0.f;
    for (int i = lane; i < NTOK / 4; i += 64) {
      float4 v = m4[i];
      sm += v.x + v.y + v.z + v.w;
    }
    sm = wred(sm);
    if (lane == 0) { *msum = sm; ((unsigned*)A.ws)[0] = 0u; }
  } else if (gwid >= 3076) {
    // ---- sr slice: plain loads/stores, no sync ----
    const int w = gwid - 3076;         // 0..SRWAVES-1
    for (int r = sr0 + w; r < sr1; r += SRWAVES) {
      const float* row = A.sr + (size_t)r * HD;
      const float4 x0 = *reinterpret_cast<const float4*>(row + lane * 4);
      const float4 x1 = *reinterpret_cast<const float4*>(row + 256 + lane * 4);
      const float4 x2 = *reinterpret_cast<const float4*>(row + 512 + lane * 4);
      float aS = wred(dot12(x0, x1, x2, A.Wsing, lane));
      float aM = wred(dot12(x0, x1, x2, A.Wmult, lane));
      if (lane == 0) { as_[r] = aS; am_[r] = aM; }
    }
  }
}

// One wave per token: dts, dem, ps[k], pm[k]. v's from ws (previous launch; L2-hot).
__global__ __launch_bounds__(256) void token_kernel(Args A) {
  const int tid  = threadIdx.x;
  const int lane = tid & 63;
  const int t    = blockIdx.x * 4 + (tid >> 6);
  if (t >= NTOK) return;
  float* F = A.ws;
  float* vS = F + 64 + 16 * HD;  float* vM = vS + 7 * HD;
  float* ps = F + 88704;         float* pm = ps + 7 * NTOK;
  float* dts = pm + 7 * NTOK;    float* dem = dts + NTOK;

  const float* tr = A.tok + (size_t)t * HD;
  const float* er = A.ent + (size_t)t * HD;
  const float4 t0 = *reinterpret_cast<const float4*>(tr + lane * 4);
  const float4 t1 = *reinterpret_cast<const float4*>(tr + 256 + lane * 4);
  const float4 t2 = *reinterpret_cast<const float4*>(tr + 512 + lane * 4);
  const float4 e0 = *reinterpret_cast<const float4*>(er + lane * 4);
  const float4 e1 = *reinterpret_cast<const float4*>(er + 256 + lane * 4);
  const float4 e2 = *reinterpret_cast<const float4*>(er + 512 + lane * 4);
  float dtsv = wred(dot12(t0, t1, t2, A.Wsing + HD, lane));
  float demv = wred(dot12(e0, e1, e2, A.Wmult + HD, lane));
  if (lane == 0) { dts[t] = dtsv; dem[t] = demv; }
  #pragma unroll
  for (int k = 0; k < 7; ++k) {
    float a = wred(dot12(t0, t1, t2, vS + k * HD, lane));
    float b = wred(dot12(t0, t1, t2, vM + k * HD, lane));
    if (lane == 0) { ps[k * NTOK + t] = a; pm[k * NTOK + t] = b; }
  }
}

// One block per batch (512 threads = tokens). R2-proven recurrence + one-shot atomic finalize.
__global__ __launch_bounds__(512) void step_kernel(Args A) {
  __shared__ unsigned sc[NR][NE];
  __shared__ double wsumD[8];
  float* F = A.ws;
  unsigned* SY = (unsigned*)A.ws;
  float* msum = F + 16;
  double* pbce = (double*)(F + 24);
  float* buS = F + 64 + 16 * HD + 14 * HD;  float* buM = buS + 8;
  float* as_ = F + 23168;       float* am_ = as_ + NSR;
  float* ps = F + 88704;        float* pm = ps + 7 * NTOK;
  float* dts = pm + 7 * NTOK;   float* dem = dts + NTOK;

  const int s = threadIdx.x;
  const int b = blockIdx.x;
  const int t = b * SL + s;
  reinterpret_cast<unsigned*>(sc)[s] = 0u;   // 512 entries exactly
  float psv[7], pmv[7], asv[8], amv[8], buSv[7], buMv[7];
  #pragma unroll
  for (int k = 0; k < 7; ++k) { psv[k] = ps[k * NTOK + t]; pmv[k] = pm[k * NTOK + t]; }
  #pragma unroll
  for (int r = 0; r < 8; ++r) { asv[r] = as_[r * NTOK + t]; amv[r] = am_[r * NTOK + t]; }
  #pragma unroll
  for (int k = 0; k < 7; ++k) { buSv[k] = buS[k]; buMv[k] = buM[k]; }
  const float dtsv = dts[t], demv = dem[t];
  const float b1 = A.bsing[0], b2 = A.bmult[0];
  const int e2 = A.e2t[t] & (NE - 1);
  const int t2 = A.t2e[t] & (NE - 1);
  __syncthreads();

  float m[8];
  float cs = 0.f, cmv = 0.f;
  double bsum = 0.0;
  #pragma unroll
  for (int r = 0; r < 8; ++r) {
    float As = cs, Am = cmv;
    #pragma unroll
    for (int j = 0; j < r; ++j) {
      As = fmaf(m[j], psv[r - 1 - j], As);
      Am = fmaf(m[j], pmv[r - 1 - j], Am);
    }
    const float xs = asv[r] + dtsv + As + b1;
    const float xm = amv[r] + demv + Am + b2;
    const float sing = 1.f / (1.f + expf(-xs));
    const float mult = 1.f / (1.f + expf(-xm));
    atomicMax(&sc[r][e2], __float_as_uint(mult));   // mult > 0: uint order == float order
    __syncthreads();
    const float pred = __uint_as_float(sc[r][t2]);  // empty segments stay 0.0f == max(.,0)
    const float merged = fmaxf(sing, pred);
    m[r] = merged;
    A.out[1 + r * NTOK + t] = merged;
    const float lab = A.labels[r * NTOK + t];
    const float p = fminf(fmaxf(merged, 1e-7f), 1.0f - 1e-7f);
    bsum += (double)(-(lab * logf(p) + (1.f - lab) * log1pf(-p)));
    if (r < 7) { cs += buSv[r]; cmv += buMv[r]; }
  }
  bsum = wredd(bsum);
  if ((s & 63) == 0) wsumD[s >> 6] = bsum;
  __syncthreads();
  if (s == 0) {
    double tot8 = 0.0;
    #pragma unroll
    for (int i = 0; i < 8; ++i) tot8 += wsumD[i];
    __hip_atomic_store(pbce + b, tot8, __ATOMIC_RELAXED, AGT);       // uncached, coherent
    unsigned k = __hip_atomic_fetch_add(SY, 1u, __ATOMIC_ACQ_REL, AGT); // one-shot, 8 total
    if (k == NB - 1) {
      double tot = 0.0;
      #pragma unroll
      for (int i = 0; i < 8; ++i)
        tot += __hip_atomic_load(pbce + i, __ATOMIC_RELAXED, AGT);
      A.out[0] = (float)(tot * (double)(*msum) / 4096.0);
    }
  }
}

extern "C" void kernel_launch(void* const* d_in, const int* in_sizes, int n_in,
                              void* d_out, int out_size, void* d_ws, size_t ws_size,
                              hipStream_t stream) {
  (void)in_sizes; (void)n_in; (void)out_size; (void)ws_size;
  Args a;
  a.labels = (const float*)d_in[0];
  a.sr     = (const float*)d_in[1];
  a.tok    = (const float*)d_in[2];
  a.ent    = (const float*)d_in[3];
  a.mask   = (const float*)d_in[4];
  a.e2t    = (const int*)d_in[5];
  a.t2e    = (const int*)d_in[6];
  a.Wsing  = (const float*)d_in[7];
  a.bsing  = (const float*)d_in[8];
  a.Wmult  = (const float*)d_in[9];
  a.bmult  = (const float*)d_in[10];
  a.Wans   = (const float*)d_in[11];
  a.bans   = (const float*)d_in[12];
  a.ws     = (float*)d_ws;
  a.out    = (float*)d_out;

  for (int k = 1; k <= 7; ++k) {
    const int sr0 = (k - 1) * SLICE;
    const int sr1 = (k * SLICE < NSR) ? k * SLICE : NSR;
    chain_sr_kernel<<<CGRID, 256, 0, stream>>>(a, k, sr0, sr1);
  }
  token_kernel<<<1024, 256, 0, stream>>>(a);
  step_kernel<<<NB, 512, 0, stream>>>(a);
}